// Round 1
// baseline (496.108 us; speedup 1.0000x reference)
//
#include <hip/hip_runtime.h>
#include <cstdint>
#include <cstddef>

// Problem constants
#define HDIM 256
#define EDIM 512
#define NB   2
#define NSQ  512
#define NSK  512

typedef __bf16 bf16x8 __attribute__((ext_vector_type(8)));
typedef float  f32x4  __attribute__((ext_vector_type(4)));

// Workspace layout (in ushort elements for the bf16 region)
#define OFF_W2F  0u          // 16 tiles x 8 s x 64 x 8  = 65536
#define OFF_W3F  65536u
#define OFF_WQEF 131072u     // 16 tiles x 16 s x 64 x 8 = 131072
#define OFF_WKEF 262144u
#define OFF_WCQ  393216u     // 32 tiles x 8 s x 64 x 8  = 131072
#define OFF_WCK  524288u
#define BF16_WS_END_BYTES 1310720u   // 655360 ushorts * 2

__device__ __forceinline__ unsigned short f2bf(float f) {
  unsigned u = __float_as_uint(f);
  u += 0x7fffu + ((u >> 16) & 1u);   // round-to-nearest-even
  return (unsigned short)(u >> 16);
}
__device__ __forceinline__ float relu_(float x) { return x > 0.f ? x : 0.f; }
__device__ __forceinline__ float softplus_(float x) {
  return fmaxf(x, 0.f) + log1pf(expf(-fabsf(x)));
}

// ---------------------------------------------------------------------------
// K1: shuffle fp32 weights into bf16 MFMA A-fragment order.
// A = W^T (A[n][k] = W[k][n]), layout [tile t][kstep s][lane][j=0..7]:
//   out[((t*S+s)*64+lane)*8 + j] = W[(s*32 + (lane>>4)*8 + j)*256 + t*16 + (lane&15)]
// ---------------------------------------------------------------------------
__global__ __launch_bounds__(64) void shuffle_weights(
    const float* __restrict__ Wqe, const float* __restrict__ Wke,
    const float* __restrict__ W1,  const float* __restrict__ Wv1,
    const float* __restrict__ W2,  const float* __restrict__ W3,
    unsigned short* __restrict__ wsb)
{
  const int bx = blockIdx.x;
  const int lane = threadIdx.x;
  const float* src; unsigned short* dst; int S; int idx;
  if      (bx <  128) { src = W2;          dst = wsb + OFF_W2F;           S = 8;  idx = bx;        }
  else if (bx <  256) { src = W3;          dst = wsb + OFF_W3F;           S = 8;  idx = bx - 128;  }
  else if (bx <  512) { src = Wqe;         dst = wsb + OFF_WQEF;          S = 16; idx = bx - 256;  }
  else if (bx <  768) { src = Wke;         dst = wsb + OFF_WKEF;          S = 16; idx = bx - 512;  }
  else if (bx <  896) { src = W1;          dst = wsb + OFF_WCQ;           S = 8;  idx = bx - 768;  }
  else if (bx < 1024) { src = Wv1;         dst = wsb + OFF_WCQ + 65536u;  S = 8;  idx = bx - 896;  }
  else if (bx < 1152) { src = W1 + 65536;  dst = wsb + OFF_WCK;           S = 8;  idx = bx - 1024; }
  else                { src = Wv1 + 65536; dst = wsb + OFF_WCK + 65536u;  S = 8;  idx = bx - 1152; }
  const int t = idx / S, s = idx % S;
  const int n  = t * 16 + (lane & 15);
  const int k0 = s * 32 + ((lane >> 4) << 3);
  unsigned short* o = dst + ((size_t)(t * S + s) * 64 + lane) * 8;
  #pragma unroll
  for (int j = 0; j < 8; ++j)
    o[j] = f2bf(src[(size_t)(k0 + j) * 256 + n]);
}

// ---------------------------------------------------------------------------
// K2: encoder + projections.
//  F  = relu(X @ We + be)               [rows, 256]
//  P  = F @ Wcat (+ b1|bv1 on q side)   [rows, 512]  (cols 0..255 = qp/kp, 256..511 = vq/vk)
// One block = 32 rows of one side. 64 blocks total.
// ---------------------------------------------------------------------------
__global__ __launch_bounds__(256) void encoder_kernel(
    const float* __restrict__ query, const float* __restrict__ key,
    const float* __restrict__ bqe,   const float* __restrict__ bke,
    const float* __restrict__ b1,    const float* __restrict__ bv1,
    const unsigned short* __restrict__ WqeF, const unsigned short* __restrict__ WkeF,
    const unsigned short* __restrict__ WcqF, const unsigned short* __restrict__ WckF,
    float* __restrict__ Pq, float* __restrict__ Pk)
{
  __shared__ unsigned short sX[32 * 520];   // X rows, bf16, pad +8
  __shared__ unsigned short sF[32 * 264];   // F rows, bf16, pad +8
  __shared__ float sBe[256];
  __shared__ float sBc[512];

  const int bx   = blockIdx.x;
  const int side = bx >> 5;          // 0 = q, 1 = k
  const int rt   = bx & 31;
  const int t    = threadIdx.x;

  const float* Xsrc = side ? key : query;
  const unsigned short* WeF = side ? WkeF : WqeF;
  const unsigned short* WcF = side ? WckF : WcqF;
  float* P = side ? Pk : Pq;

  {
    const int m = t >> 3, ch = t & 7;
    const int c0 = ch * 64;
    const float* xr = Xsrc + (size_t)(rt * 32 + m) * EDIM;
    #pragma unroll
    for (int cc = 0; cc < 64; cc += 4) {
      const int c = c0 + cc;
      float4 xv = *(const float4*)(xr + c);
      ushort4 xb;
      xb.x = f2bf(xv.x); xb.y = f2bf(xv.y); xb.z = f2bf(xv.z); xb.w = f2bf(xv.w);
      *(ushort4*)&sX[m * 520 + c] = xb;
    }
    sBe[t]       = side ? bke[t] : bqe[t];
    sBc[t]       = side ? 0.f : b1[t];
    sBc[256 + t] = side ? 0.f : bv1[t];
  }
  __syncthreads();

  const int wave = t >> 6, lane = t & 63;
  const int l15 = lane & 15, q4 = lane >> 4;

  // GEMM1e: D[n][m] = sum_k We[k][n] * X[m][k], K = 512 (16 k-steps)
  f32x4 acc1[4][2];
  #pragma unroll
  for (int ft = 0; ft < 4; ++ft)
    #pragma unroll
    for (int pt = 0; pt < 2; ++pt)
      acc1[ft][pt] = (f32x4){0.f, 0.f, 0.f, 0.f};

  for (int s = 0; s < 16; ++s) {
    bf16x8 af[4], bfr[2];
    #pragma unroll
    for (int ft = 0; ft < 4; ++ft) {
      const int tg = wave * 4 + ft;
      af[ft] = *(const bf16x8*)(WeF + ((size_t)(tg * 16 + s) * 64 + lane) * 8);
    }
    #pragma unroll
    for (int pt = 0; pt < 2; ++pt)
      bfr[pt] = *(const bf16x8*)&sX[(pt * 16 + l15) * 520 + s * 32 + q4 * 8];
    #pragma unroll
    for (int ft = 0; ft < 4; ++ft)
      #pragma unroll
      for (int pt = 0; pt < 2; ++pt)
        acc1[ft][pt] = __builtin_amdgcn_mfma_f32_16x16x32_bf16(af[ft], bfr[pt], acc1[ft][pt], 0, 0, 0);
  }

  // Epilogue 1: F = relu(D + be) -> bf16 LDS [m][n]
  #pragma unroll
  for (int ft = 0; ft < 4; ++ft) {
    const int tg = wave * 4 + ft;
    const int n0 = tg * 16 + q4 * 4;
    float4 b4 = *(const float4*)&sBe[n0];
    #pragma unroll
    for (int pt = 0; pt < 2; ++pt) {
      const int mr = pt * 16 + l15;
      f32x4 a = acc1[ft][pt];
      ushort4 h;
      h.x = f2bf(relu_(a[0] + b4.x));
      h.y = f2bf(relu_(a[1] + b4.y));
      h.z = f2bf(relu_(a[2] + b4.z));
      h.w = f2bf(relu_(a[3] + b4.w));
      *(ushort4*)&sF[mr * 264 + n0] = h;
    }
  }
  __syncthreads();

  // GEMM2e: P[n][m] = sum_k Wcat[k][n] * F[m][k], nout = 512 (32 tiles), K = 256 (8 steps)
  f32x4 acc2[8][2];
  #pragma unroll
  for (int ft = 0; ft < 8; ++ft)
    #pragma unroll
    for (int pt = 0; pt < 2; ++pt)
      acc2[ft][pt] = (f32x4){0.f, 0.f, 0.f, 0.f};

  for (int s = 0; s < 8; ++s) {
    bf16x8 af[8], bfr[2];
    #pragma unroll
    for (int ft = 0; ft < 8; ++ft) {
      const int tg = wave * 8 + ft;
      af[ft] = *(const bf16x8*)(WcF + ((size_t)(tg * 8 + s) * 64 + lane) * 8);
    }
    #pragma unroll
    for (int pt = 0; pt < 2; ++pt)
      bfr[pt] = *(const bf16x8*)&sF[(pt * 16 + l15) * 264 + s * 32 + q4 * 8];
    #pragma unroll
    for (int ft = 0; ft < 8; ++ft)
      #pragma unroll
      for (int pt = 0; pt < 2; ++pt)
        acc2[ft][pt] = __builtin_amdgcn_mfma_f32_16x16x32_bf16(af[ft], bfr[pt], acc2[ft][pt], 0, 0, 0);
  }

  // Epilogue 2: store P[row][n] = D + bias (fp32, no relu)
  #pragma unroll
  for (int ft = 0; ft < 8; ++ft) {
    const int tg = wave * 8 + ft;
    const int n0 = tg * 16 + q4 * 4;
    float4 bc = *(const float4*)&sBc[n0];
    #pragma unroll
    for (int pt = 0; pt < 2; ++pt) {
      const int mr = pt * 16 + l15;
      const int row = rt * 32 + mr;
      f32x4 a = acc2[ft][pt];
      float4 o;
      o.x = a[0] + bc.x; o.y = a[1] + bc.y; o.z = a[2] + bc.z; o.w = a[3] + bc.w;
      *(float4*)&P[(size_t)row * 512 + n0] = o;
    }
  }
}

// ---------------------------------------------------------------------------
// K3: fused pair kernel. One block = (b, q, 64 consecutive k).
//   X1 = relu(qp' + kp)            (LDS bf16 [64][256+8])
//   H1 = relu(X1 @ W2 + b2)        (MFMA, transposed-out, back into same LDS)
//   H2 = relu(H1 @ W3 + b3)        (MFMA)
//   logit = H2 . Wf + bf           (epilogue reduce)
//   var   = softplus(relu(vq'+vk) . Wv2 + bv2)   (VALU, during staging)
// ---------------------------------------------------------------------------
__global__ __launch_bounds__(256) void pair_kernel(
    const float* __restrict__ Pq, const float* __restrict__ Pk,
    const unsigned short* __restrict__ W2F, const unsigned short* __restrict__ W3F,
    const float* __restrict__ b2, const float* __restrict__ b3,
    const float* __restrict__ Wf, const float* __restrict__ bfp,
    const float* __restrict__ Wv2, const float* __restrict__ bv2p,
    float* __restrict__ out)
{
  __shared__ unsigned short sXH[64 * 264];   // X1 then H1, bf16, pad +8
  __shared__ float sB2[256], sB3[256], sWf[256];
  __shared__ float sRed[4][64];
  __shared__ float sVred[64][4];

  const int kt = blockIdx.x, qy = blockIdx.y, bz = blockIdx.z;
  const int t = threadIdx.x;
  const float* qpRow = Pq + (size_t)(bz * NSQ + qy) * 512;

  // --- staging: X1 build + variance head (VALU) ---
  {
    const int m = t >> 2, jj = t & 3;
    const int c0 = jj * 64;
    const float* kpRow = Pk + (size_t)(bz * NSK + kt * 64 + m) * 512;
    float vpart = 0.f;
    #pragma unroll
    for (int cc = 0; cc < 64; cc += 4) {
      const int c = c0 + cc;
      float4 qv = *(const float4*)(qpRow + c);
      float4 kv = *(const float4*)(kpRow + c);
      ushort4 hb;
      hb.x = f2bf(relu_(qv.x + kv.x));
      hb.y = f2bf(relu_(qv.y + kv.y));
      hb.z = f2bf(relu_(qv.z + kv.z));
      hb.w = f2bf(relu_(qv.w + kv.w));
      *(ushort4*)&sXH[m * 264 + c] = hb;
      float4 av = *(const float4*)(qpRow + 256 + c);
      float4 bv = *(const float4*)(kpRow + 256 + c);
      float4 wv = *(const float4*)(Wv2 + c);
      vpart += relu_(av.x + bv.x) * wv.x + relu_(av.y + bv.y) * wv.y
             + relu_(av.z + bv.z) * wv.z + relu_(av.w + bv.w) * wv.w;
    }
    sVred[m][jj] = vpart;
    sB2[t] = b2[t]; sB3[t] = b3[t]; sWf[t] = Wf[t];
  }
  __syncthreads();

  const int wave = t >> 6, lane = t & 63;
  const int l15 = lane & 15, q4 = lane >> 4;

  // --- GEMM1: D1[n][m] = sum_k W2[k][n] * X1[m][k] ---
  f32x4 acc[4][4];
  #pragma unroll
  for (int ft = 0; ft < 4; ++ft)
    #pragma unroll
    for (int pt = 0; pt < 4; ++pt)
      acc[ft][pt] = (f32x4){0.f, 0.f, 0.f, 0.f};

  for (int s = 0; s < 8; ++s) {
    bf16x8 af[4], bfr[4];
    #pragma unroll
    for (int ft = 0; ft < 4; ++ft) {
      const int tg = wave * 4 + ft;
      af[ft] = *(const bf16x8*)(W2F + ((size_t)(tg * 8 + s) * 64 + lane) * 8);
    }
    #pragma unroll
    for (int pt = 0; pt < 4; ++pt)
      bfr[pt] = *(const bf16x8*)&sXH[(pt * 16 + l15) * 264 + s * 32 + q4 * 8];
    #pragma unroll
    for (int ft = 0; ft < 4; ++ft)
      #pragma unroll
      for (int pt = 0; pt < 4; ++pt)
        acc[ft][pt] = __builtin_amdgcn_mfma_f32_16x16x32_bf16(af[ft], bfr[pt], acc[ft][pt], 0, 0, 0);
  }
  __syncthreads();   // all X1 reads done before overwrite

  // --- Epilogue 1: H1 = relu(D1 + b2) -> bf16, same LDS buffer, layout [m][n] ---
  #pragma unroll
  for (int ft = 0; ft < 4; ++ft) {
    const int tg = wave * 4 + ft;
    const int n0 = tg * 16 + q4 * 4;
    float4 b4 = *(const float4*)&sB2[n0];
    #pragma unroll
    for (int pt = 0; pt < 4; ++pt) {
      const int mr = pt * 16 + l15;
      f32x4 a = acc[ft][pt];
      ushort4 h;
      h.x = f2bf(relu_(a[0] + b4.x));
      h.y = f2bf(relu_(a[1] + b4.y));
      h.z = f2bf(relu_(a[2] + b4.z));
      h.w = f2bf(relu_(a[3] + b4.w));
      *(ushort4*)&sXH[mr * 264 + n0] = h;
    }
  }
  __syncthreads();

  // --- GEMM2: D2[n][m] = sum_k W3[k][n] * H1[m][k] ---
  f32x4 acc2[4][4];
  #pragma unroll
  for (int ft = 0; ft < 4; ++ft)
    #pragma unroll
    for (int pt = 0; pt < 4; ++pt)
      acc2[ft][pt] = (f32x4){0.f, 0.f, 0.f, 0.f};

  for (int s = 0; s < 8; ++s) {
    bf16x8 af[4], bfr[4];
    #pragma unroll
    for (int ft = 0; ft < 4; ++ft) {
      const int tg = wave * 4 + ft;
      af[ft] = *(const bf16x8*)(W3F + ((size_t)(tg * 8 + s) * 64 + lane) * 8);
    }
    #pragma unroll
    for (int pt = 0; pt < 4; ++pt)
      bfr[pt] = *(const bf16x8*)&sXH[(pt * 16 + l15) * 264 + s * 32 + q4 * 8];
    #pragma unroll
    for (int ft = 0; ft < 4; ++ft)
      #pragma unroll
      for (int pt = 0; pt < 4; ++pt)
        acc2[ft][pt] = __builtin_amdgcn_mfma_f32_16x16x32_bf16(af[ft], bfr[pt], acc2[ft][pt], 0, 0, 0);
  }

  // --- Final epilogue: logit partials, reduce over feature dim ---
  float p[4] = {0.f, 0.f, 0.f, 0.f};
  #pragma unroll
  for (int ft = 0; ft < 4; ++ft) {
    const int tg = wave * 4 + ft;
    const int n0 = tg * 16 + q4 * 4;
    float4 b4 = *(const float4*)&sB3[n0];
    float4 w4 = *(const float4*)&sWf[n0];
    #pragma unroll
    for (int pt = 0; pt < 4; ++pt) {
      f32x4 a = acc2[ft][pt];
      p[pt] += relu_(a[0] + b4.x) * w4.x + relu_(a[1] + b4.y) * w4.y
             + relu_(a[2] + b4.z) * w4.z + relu_(a[3] + b4.w) * w4.w;
    }
  }
  #pragma unroll
  for (int pt = 0; pt < 4; ++pt) {
    float v = p[pt];
    v += __shfl_xor(v, 16, 64);
    v += __shfl_xor(v, 32, 64);
    if (lane < 16) sRed[wave][pt * 16 + lane] = v;
  }
  __syncthreads();

  if (t < 64) {
    const size_t o = (size_t)(bz * NSQ + qy) * NSK + kt * 64 + t;
    float lg = bfp[0] + sRed[0][t] + sRed[1][t] + sRed[2][t] + sRed[3][t];
    out[o] = lg;
    float vs = bv2p[0] + sVred[t][0] + sVred[t][1] + sVred[t][2] + sVred[t][3];
    out[(size_t)NB * NSQ * NSK + o] = softplus_(vs);
  }
}

// ---------------------------------------------------------------------------
extern "C" void kernel_launch(void* const* d_in, const int* in_sizes, int n_in,
                              void* d_out, int out_size, void* d_ws, size_t ws_size,
                              hipStream_t stream)
{
  (void)in_sizes; (void)n_in; (void)out_size; (void)ws_size;
  const float* query = (const float*)d_in[0];
  const float* key   = (const float*)d_in[1];
  const float* Wqe   = (const float*)d_in[2];
  const float* bqe   = (const float*)d_in[3];
  const float* Wke   = (const float*)d_in[4];
  const float* bke   = (const float*)d_in[5];
  const float* W1    = (const float*)d_in[6];
  const float* b1    = (const float*)d_in[7];
  const float* W2    = (const float*)d_in[8];
  const float* b2    = (const float*)d_in[9];
  const float* W3    = (const float*)d_in[10];
  const float* b3    = (const float*)d_in[11];
  const float* Wf    = (const float*)d_in[12];
  const float* bf    = (const float*)d_in[13];
  const float* Wv1   = (const float*)d_in[14];
  const float* bv1   = (const float*)d_in[15];
  const float* Wv2   = (const float*)d_in[16];
  const float* bv2   = (const float*)d_in[17];

  unsigned short* wsb = (unsigned short*)d_ws;
  float* Pq = (float*)((char*)d_ws + BF16_WS_END_BYTES);   // [1024][512]
  float* Pk = Pq + (size_t)1024 * 512;                     // [1024][512]
  float* out = (float*)d_out;

  shuffle_weights<<<1280, 64, 0, stream>>>(Wqe, Wke, W1, Wv1, W2, W3, wsb);
  encoder_kernel<<<64, 256, 0, stream>>>(query, key, bqe, bke, b1, bv1,
      wsb + OFF_WQEF, wsb + OFF_WKEF, wsb + OFF_WCQ, wsb + OFF_WCK, Pq, Pk);
  pair_kernel<<<dim3(NSK / 64, NSQ, NB), 256, 0, stream>>>(Pq, Pk,
      wsb + OFF_W2F, wsb + OFF_W3F, b2, b3, Wf, bf, Wv2, bv2, out);
}

// Round 2
// 285.942 us; speedup vs baseline: 1.7350x; 1.7350x over previous
//
#include <hip/hip_runtime.h>
#include <cstdint>
#include <cstddef>

// Problem constants
#define HDIM 256
#define EDIM 512
#define NB   2
#define NSQ  512
#define NSK  512

typedef __bf16 bf16x8 __attribute__((ext_vector_type(8)));
typedef float  f32x4  __attribute__((ext_vector_type(4)));
typedef unsigned short u16x8 __attribute__((ext_vector_type(8)));

// Workspace layout (in ushort elements for the bf16 region)
#define OFF_W2F  0u          // 16 tiles x 8 s x 64 x 8  = 65536
#define OFF_W3F  65536u
#define OFF_WQEF 131072u     // 16 tiles x 16 s x 64 x 8 = 131072
#define OFF_WKEF 262144u
#define OFF_WCQ  393216u     // 32 tiles x 8 s x 64 x 8  = 131072
#define OFF_WCK  524288u
#define BF16_WS_END_BYTES 1310720u   // 655360 ushorts * 2

__device__ __forceinline__ unsigned short f2bf(float f) {
  unsigned u = __float_as_uint(f);
  u += 0x7fffu + ((u >> 16) & 1u);   // round-to-nearest-even
  return (unsigned short)(u >> 16);
}
__device__ __forceinline__ float relu_(float x) { return x > 0.f ? x : 0.f; }
__device__ __forceinline__ float softplus_(float x) {
  return fmaxf(x, 0.f) + log1pf(expf(-fabsf(x)));
}

// ---------------------------------------------------------------------------
// K1: shuffle fp32 weights into bf16 MFMA A-fragment order (unchanged).
// A = W^T (A[n][k] = W[k][n]), layout [tile t][kstep s][lane][j=0..7]:
//   out[((t*S+s)*64+lane)*8 + j] = W[(s*32 + (lane>>4)*8 + j)*256 + t*16 + (lane&15)]
// ---------------------------------------------------------------------------
__global__ __launch_bounds__(64) void shuffle_weights(
    const float* __restrict__ Wqe, const float* __restrict__ Wke,
    const float* __restrict__ W1,  const float* __restrict__ Wv1,
    const float* __restrict__ W2,  const float* __restrict__ W3,
    unsigned short* __restrict__ wsb)
{
  const int bx = blockIdx.x;
  const int lane = threadIdx.x;
  const float* src; unsigned short* dst; int S; int idx;
  if      (bx <  128) { src = W2;          dst = wsb + OFF_W2F;           S = 8;  idx = bx;        }
  else if (bx <  256) { src = W3;          dst = wsb + OFF_W3F;           S = 8;  idx = bx - 128;  }
  else if (bx <  512) { src = Wqe;         dst = wsb + OFF_WQEF;          S = 16; idx = bx - 256;  }
  else if (bx <  768) { src = Wke;         dst = wsb + OFF_WKEF;          S = 16; idx = bx - 512;  }
  else if (bx <  896) { src = W1;          dst = wsb + OFF_WCQ;           S = 8;  idx = bx - 768;  }
  else if (bx < 1024) { src = Wv1;         dst = wsb + OFF_WCQ + 65536u;  S = 8;  idx = bx - 896;  }
  else if (bx < 1152) { src = W1 + 65536;  dst = wsb + OFF_WCK;           S = 8;  idx = bx - 1024; }
  else                { src = Wv1 + 65536; dst = wsb + OFF_WCK + 65536u;  S = 8;  idx = bx - 1152; }
  const int t = idx / S, s = idx % S;
  const int n  = t * 16 + (lane & 15);
  const int k0 = s * 32 + ((lane >> 4) << 3);
  unsigned short* o = dst + ((size_t)(t * S + s) * 64 + lane) * 8;
  #pragma unroll
  for (int j = 0; j < 8; ++j)
    o[j] = f2bf(src[(size_t)(k0 + j) * 256 + n]);
}

// ---------------------------------------------------------------------------
// K2: encoder + projections (unchanged).
// ---------------------------------------------------------------------------
__global__ __launch_bounds__(256) void encoder_kernel(
    const float* __restrict__ query, const float* __restrict__ key,
    const float* __restrict__ bqe,   const float* __restrict__ bke,
    const float* __restrict__ b1,    const float* __restrict__ bv1,
    const unsigned short* __restrict__ WqeF, const unsigned short* __restrict__ WkeF,
    const unsigned short* __restrict__ WcqF, const unsigned short* __restrict__ WckF,
    float* __restrict__ Pq, float* __restrict__ Pk)
{
  __shared__ unsigned short sX[32 * 520];   // X rows, bf16, pad +8
  __shared__ unsigned short sF[32 * 264];   // F rows, bf16, pad +8
  __shared__ float sBe[256];
  __shared__ float sBc[512];

  const int bx   = blockIdx.x;
  const int side = bx >> 5;          // 0 = q, 1 = k
  const int rt   = bx & 31;
  const int t    = threadIdx.x;

  const float* Xsrc = side ? key : query;
  const unsigned short* WeF = side ? WkeF : WqeF;
  const unsigned short* WcF = side ? WckF : WcqF;
  float* P = side ? Pk : Pq;

  {
    const int m = t >> 3, ch = t & 7;
    const int c0 = ch * 64;
    const float* xr = Xsrc + (size_t)(rt * 32 + m) * EDIM;
    #pragma unroll
    for (int cc = 0; cc < 64; cc += 4) {
      const int c = c0 + cc;
      float4 xv = *(const float4*)(xr + c);
      ushort4 xb;
      xb.x = f2bf(xv.x); xb.y = f2bf(xv.y); xb.z = f2bf(xv.z); xb.w = f2bf(xv.w);
      *(ushort4*)&sX[m * 520 + c] = xb;
    }
    sBe[t]       = side ? bke[t] : bqe[t];
    sBc[t]       = side ? 0.f : b1[t];
    sBc[256 + t] = side ? 0.f : bv1[t];
  }
  __syncthreads();

  const int wave = t >> 6, lane = t & 63;
  const int l15 = lane & 15, q4 = lane >> 4;

  // GEMM1e: D[n][m] = sum_k We[k][n] * X[m][k], K = 512 (16 k-steps)
  f32x4 acc1[4][2];
  #pragma unroll
  for (int ft = 0; ft < 4; ++ft)
    #pragma unroll
    for (int pt = 0; pt < 2; ++pt)
      acc1[ft][pt] = (f32x4){0.f, 0.f, 0.f, 0.f};

  for (int s = 0; s < 16; ++s) {
    bf16x8 af[4], bfr[2];
    #pragma unroll
    for (int ft = 0; ft < 4; ++ft) {
      const int tg = wave * 4 + ft;
      af[ft] = *(const bf16x8*)(WeF + ((size_t)(tg * 16 + s) * 64 + lane) * 8);
    }
    #pragma unroll
    for (int pt = 0; pt < 2; ++pt)
      bfr[pt] = *(const bf16x8*)&sX[(pt * 16 + l15) * 520 + s * 32 + q4 * 8];
    #pragma unroll
    for (int ft = 0; ft < 4; ++ft)
      #pragma unroll
      for (int pt = 0; pt < 2; ++pt)
        acc1[ft][pt] = __builtin_amdgcn_mfma_f32_16x16x32_bf16(af[ft], bfr[pt], acc1[ft][pt], 0, 0, 0);
  }

  // Epilogue 1: F = relu(D + be) -> bf16 LDS [m][n]
  #pragma unroll
  for (int ft = 0; ft < 4; ++ft) {
    const int tg = wave * 4 + ft;
    const int n0 = tg * 16 + q4 * 4;
    float4 b4 = *(const float4*)&sBe[n0];
    #pragma unroll
    for (int pt = 0; pt < 2; ++pt) {
      const int mr = pt * 16 + l15;
      f32x4 a = acc1[ft][pt];
      ushort4 h;
      h.x = f2bf(relu_(a[0] + b4.x));
      h.y = f2bf(relu_(a[1] + b4.y));
      h.z = f2bf(relu_(a[2] + b4.z));
      h.w = f2bf(relu_(a[3] + b4.w));
      *(ushort4*)&sF[mr * 264 + n0] = h;
    }
  }
  __syncthreads();

  // GEMM2e: P[n][m] = sum_k Wcat[k][n] * F[m][k], nout = 512 (32 tiles), K = 256 (8 steps)
  f32x4 acc2[8][2];
  #pragma unroll
  for (int ft = 0; ft < 8; ++ft)
    #pragma unroll
    for (int pt = 0; pt < 2; ++pt)
      acc2[ft][pt] = (f32x4){0.f, 0.f, 0.f, 0.f};

  for (int s = 0; s < 8; ++s) {
    bf16x8 af[8], bfr[2];
    #pragma unroll
    for (int ft = 0; ft < 8; ++ft) {
      const int tg = wave * 8 + ft;
      af[ft] = *(const bf16x8*)(WcF + ((size_t)(tg * 8 + s) * 64 + lane) * 8);
    }
    #pragma unroll
    for (int pt = 0; pt < 2; ++pt)
      bfr[pt] = *(const bf16x8*)&sF[(pt * 16 + l15) * 264 + s * 32 + q4 * 8];
    #pragma unroll
    for (int ft = 0; ft < 8; ++ft)
      #pragma unroll
      for (int pt = 0; pt < 2; ++pt)
        acc2[ft][pt] = __builtin_amdgcn_mfma_f32_16x16x32_bf16(af[ft], bfr[pt], acc2[ft][pt], 0, 0, 0);
  }

  // Epilogue 2: store P[row][n] = D + bias (fp32, no relu)
  #pragma unroll
  for (int ft = 0; ft < 8; ++ft) {
    const int tg = wave * 8 + ft;
    const int n0 = tg * 16 + q4 * 4;
    float4 bc = *(const float4*)&sBc[n0];
    #pragma unroll
    for (int pt = 0; pt < 2; ++pt) {
      const int mr = pt * 16 + l15;
      const int row = rt * 32 + mr;
      f32x4 a = acc2[ft][pt];
      float4 o;
      o.x = a[0] + bc.x; o.y = a[1] + bc.y; o.z = a[2] + bc.z; o.w = a[3] + bc.w;
      *(float4*)&P[(size_t)row * 512 + n0] = o;
    }
  }
}

// ---------------------------------------------------------------------------
// K3: fused pair kernel. One block = (b, q, 64 consecutive k). 512 threads.
// 8 waves; wave w owns n-tiles {2w, 2w+1} (32 n-cols), all 64 m.
// LDS XOR swizzle: 16B chunk c of row m stored at chunk c ^ (m&7).
//   X1 = relu(qp' + kp)            (LDS bf16, swizzled [64][256])
//   H1 = relu(X1 @ W2 + b2)        (MFMA transposed-out, same LDS)
//   H2 = relu(H1 @ W3 + b3)        (MFMA)
//   logit = H2 . Wf + bf
//   var   = softplus(relu(vq'+vk) . Wv2 + bv2)   (VALU, during staging)
// ---------------------------------------------------------------------------
__global__ __launch_bounds__(512, 6) void pair_kernel(
    const float* __restrict__ Pq, const float* __restrict__ Pk,
    const unsigned short* __restrict__ W2F, const unsigned short* __restrict__ W3F,
    const float* __restrict__ b2, const float* __restrict__ b3,
    const float* __restrict__ Wf, const float* __restrict__ bfp,
    const float* __restrict__ Wv2, const float* __restrict__ bv2p,
    float* __restrict__ out)
{
  // Manual LDS carving; sRed aliases dead sB2/sB3 (guarded by a barrier).
  __shared__ __align__(16) unsigned char smem[37888];
  unsigned short* sXH = (unsigned short*)smem;        // 64*256 bf16 = 32768 B
  float* sB2   = (float*)(smem + 32768);              // 1024 B
  float* sB3   = (float*)(smem + 33792);              // 1024 B
  float* sWf   = (float*)(smem + 34816);              // 1024 B
  float* sVred = (float*)(smem + 35840);              // 64*8 = 2048 B
  float* sRed  = (float*)(smem + 32768);              // 8*64 = 2048 B (alias)

  const int kt = blockIdx.x, qy = blockIdx.y, bz = blockIdx.z;
  const int t = threadIdx.x;
  const float* qpRow = Pq + (size_t)(bz * NSQ + qy) * 512;

  // --- staging: X1 build (swizzled) + variance head (VALU) ---
  {
    const int m   = t >> 3;     // 0..63 pair row
    const int sub = t & 7;      // 0..7
    const float* kpRow = Pk + (size_t)(bz * NSK + kt * 64 + m) * 512;
    const int msw = (m & 7);
    float vpart = 0.f;
    #pragma unroll
    for (int it = 0; it < 4; ++it) {
      const int c = it * 64 + sub * 8;      // 8 consecutive cols
      float4 q0 = *(const float4*)(qpRow + c);
      float4 q1 = *(const float4*)(qpRow + c + 4);
      float4 k0 = *(const float4*)(kpRow + c);
      float4 k1 = *(const float4*)(kpRow + c + 4);
      u16x8 hb;
      hb[0] = f2bf(relu_(q0.x + k0.x));
      hb[1] = f2bf(relu_(q0.y + k0.y));
      hb[2] = f2bf(relu_(q0.z + k0.z));
      hb[3] = f2bf(relu_(q0.w + k0.w));
      hb[4] = f2bf(relu_(q1.x + k1.x));
      hb[5] = f2bf(relu_(q1.y + k1.y));
      hb[6] = f2bf(relu_(q1.z + k1.z));
      hb[7] = f2bf(relu_(q1.w + k1.w));
      const int chunk = (c >> 3) ^ msw;     // XOR swizzle
      *(u16x8*)&sXH[m * 256 + chunk * 8] = hb;
      // variance head partial
      float4 a0 = *(const float4*)(qpRow + 256 + c);
      float4 a1 = *(const float4*)(qpRow + 256 + c + 4);
      float4 v0 = *(const float4*)(kpRow + 256 + c);
      float4 v1 = *(const float4*)(kpRow + 256 + c + 4);
      float4 w0 = *(const float4*)(Wv2 + c);
      float4 w1 = *(const float4*)(Wv2 + c + 4);
      vpart += relu_(a0.x + v0.x) * w0.x + relu_(a0.y + v0.y) * w0.y
             + relu_(a0.z + v0.z) * w0.z + relu_(a0.w + v0.w) * w0.w
             + relu_(a1.x + v1.x) * w1.x + relu_(a1.y + v1.y) * w1.y
             + relu_(a1.z + v1.z) * w1.z + relu_(a1.w + v1.w) * w1.w;
    }
    sVred[m * 8 + sub] = vpart;
    if (t < 256) { sB2[t] = b2[t]; sB3[t] = b3[t]; sWf[t] = Wf[t]; }
  }
  __syncthreads();

  const int wave = t >> 6, lane = t & 63;
  const int l15 = lane & 15, q4 = lane >> 4;
  const int lsw = l15 & 7;

  // --- GEMM1: D1[n][m] = sum_k W2[k][n] * X1[m][k] ---
  f32x4 acc[2][4];
  #pragma unroll
  for (int ft = 0; ft < 2; ++ft)
    #pragma unroll
    for (int pt = 0; pt < 4; ++pt)
      acc[ft][pt] = (f32x4){0.f, 0.f, 0.f, 0.f};

  #pragma unroll
  for (int s = 0; s < 8; ++s) {
    bf16x8 af[2], bfr[4];
    #pragma unroll
    for (int ft = 0; ft < 2; ++ft) {
      const int tg = wave * 2 + ft;
      af[ft] = *(const bf16x8*)(W2F + ((size_t)(tg * 8 + s) * 64 + lane) * 8);
    }
    #pragma unroll
    for (int pt = 0; pt < 4; ++pt) {
      const int chunk = ((s << 2) + q4) ^ lsw;
      bfr[pt] = *(const bf16x8*)&sXH[(pt * 16 + l15) * 256 + chunk * 8];
    }
    #pragma unroll
    for (int ft = 0; ft < 2; ++ft)
      #pragma unroll
      for (int pt = 0; pt < 4; ++pt)
        acc[ft][pt] = __builtin_amdgcn_mfma_f32_16x16x32_bf16(af[ft], bfr[pt], acc[ft][pt], 0, 0, 0);
  }
  __syncthreads();   // all X1 reads done before overwrite

  // --- Epilogue 1: H1 = relu(D1 + b2) -> bf16, same LDS buffer (swizzled) ---
  #pragma unroll
  for (int ft = 0; ft < 2; ++ft) {
    const int tg = wave * 2 + ft;
    const int n0 = tg * 16 + q4 * 4;
    float4 b4 = *(const float4*)&sB2[n0];
    const int chunkS = ((n0 >> 3) ^ lsw);
    #pragma unroll
    for (int pt = 0; pt < 4; ++pt) {
      const int mr = pt * 16 + l15;
      f32x4 a = acc[ft][pt];
      ushort4 h;
      h.x = f2bf(relu_(a[0] + b4.x));
      h.y = f2bf(relu_(a[1] + b4.y));
      h.z = f2bf(relu_(a[2] + b4.z));
      h.w = f2bf(relu_(a[3] + b4.w));
      *(ushort4*)&sXH[mr * 256 + chunkS * 8 + (n0 & 7)] = h;
    }
  }
  __syncthreads();

  // --- GEMM2: D2[n][m] = sum_k W3[k][n] * H1[m][k] ---
  f32x4 acc2[2][4];
  #pragma unroll
  for (int ft = 0; ft < 2; ++ft)
    #pragma unroll
    for (int pt = 0; pt < 4; ++pt)
      acc2[ft][pt] = (f32x4){0.f, 0.f, 0.f, 0.f};

  #pragma unroll
  for (int s = 0; s < 8; ++s) {
    bf16x8 af[2], bfr[4];
    #pragma unroll
    for (int ft = 0; ft < 2; ++ft) {
      const int tg = wave * 2 + ft;
      af[ft] = *(const bf16x8*)(W3F + ((size_t)(tg * 8 + s) * 64 + lane) * 8);
    }
    #pragma unroll
    for (int pt = 0; pt < 4; ++pt) {
      const int chunk = ((s << 2) + q4) ^ lsw;
      bfr[pt] = *(const bf16x8*)&sXH[(pt * 16 + l15) * 256 + chunk * 8];
    }
    #pragma unroll
    for (int ft = 0; ft < 2; ++ft)
      #pragma unroll
      for (int pt = 0; pt < 4; ++pt)
        acc2[ft][pt] = __builtin_amdgcn_mfma_f32_16x16x32_bf16(af[ft], bfr[pt], acc2[ft][pt], 0, 0, 0);
  }

  // --- Final epilogue: logit partials over this wave's 32 n-cols ---
  float p[4] = {0.f, 0.f, 0.f, 0.f};
  #pragma unroll
  for (int ft = 0; ft < 2; ++ft) {
    const int tg = wave * 2 + ft;
    const int n0 = tg * 16 + q4 * 4;
    float4 b4 = *(const float4*)&sB3[n0];
    float4 w4 = *(const float4*)&sWf[n0];
    #pragma unroll
    for (int pt = 0; pt < 4; ++pt) {
      f32x4 a = acc2[ft][pt];
      p[pt] += relu_(a[0] + b4.x) * w4.x + relu_(a[1] + b4.y) * w4.y
             + relu_(a[2] + b4.z) * w4.z + relu_(a[3] + b4.w) * w4.w;
    }
  }
  __syncthreads();   // sB2/sB3 reads done before sRed (alias) writes
  #pragma unroll
  for (int pt = 0; pt < 4; ++pt) {
    float v = p[pt];
    v += __shfl_xor(v, 16, 64);
    v += __shfl_xor(v, 32, 64);
    if (lane < 16) sRed[wave * 64 + pt * 16 + lane] = v;
  }
  __syncthreads();

  if (t < 64) {
    const size_t o = (size_t)(bz * NSQ + qy) * NSK + kt * 64 + t;
    float lg = bfp[0];
    #pragma unroll
    for (int w = 0; w < 8; ++w) lg += sRed[w * 64 + t];
    out[o] = lg;
    float vs = bv2p[0];
    #pragma unroll
    for (int j = 0; j < 8; ++j) vs += sVred[t * 8 + j];
    out[(size_t)NB * NSQ * NSK + o] = softplus_(vs);
  }
}

// ---------------------------------------------------------------------------
extern "C" void kernel_launch(void* const* d_in, const int* in_sizes, int n_in,
                              void* d_out, int out_size, void* d_ws, size_t ws_size,
                              hipStream_t stream)
{
  (void)in_sizes; (void)n_in; (void)out_size; (void)ws_size;
  const float* query = (const float*)d_in[0];
  const float* key   = (const float*)d_in[1];
  const float* Wqe   = (const float*)d_in[2];
  const float* bqe   = (const float*)d_in[3];
  const float* Wke   = (const float*)d_in[4];
  const float* bke   = (const float*)d_in[5];
  const float* W1    = (const float*)d_in[6];
  const float* b1    = (const float*)d_in[7];
  const float* W2    = (const float*)d_in[8];
  const float* b2    = (const float*)d_in[9];
  const float* W3    = (const float*)d_in[10];
  const float* b3    = (const float*)d_in[11];
  const float* Wf    = (const float*)d_in[12];
  const float* bf    = (const float*)d_in[13];
  const float* Wv1   = (const float*)d_in[14];
  const float* bv1   = (const float*)d_in[15];
  const float* Wv2   = (const float*)d_in[16];
  const float* bv2   = (const float*)d_in[17];

  unsigned short* wsb = (unsigned short*)d_ws;
  float* Pq = (float*)((char*)d_ws + BF16_WS_END_BYTES);   // [1024][512]
  float* Pk = Pq + (size_t)1024 * 512;                     // [1024][512]
  float* out = (float*)d_out;

  shuffle_weights<<<1280, 64, 0, stream>>>(Wqe, Wke, W1, Wv1, W2, W3, wsb);
  encoder_kernel<<<64, 256, 0, stream>>>(query, key, bqe, bke, b1, bv1,
      wsb + OFF_WQEF, wsb + OFF_WKEF, wsb + OFF_WCQ, wsb + OFF_WCK, Pq, Pk);
  pair_kernel<<<dim3(NSK / 64, NSQ, NB), 512, 0, stream>>>(Pq, Pk,
      wsb + OFF_W2F, wsb + OFF_W3F, b2, b3, Wf, bf, Wv2, bv2, out);
}